// Round 1
// baseline (502.781 us; speedup 1.0000x reference)
//
#include <hip/hip_runtime.h>

typedef __attribute__((ext_vector_type(8))) short short8;
typedef __attribute__((ext_vector_type(4))) float f32x4;
typedef unsigned short ushort_t;
typedef unsigned int u32;
typedef unsigned long long u64;

#define MFMA16(a,b,c) __builtin_amdgcn_mfma_f32_16x16x32_bf16((a),(b),(c),0,0,0)

__device__ __forceinline__ ushort_t f2bf(float f){
  union { float f; u32 u; } v; v.f = f;
  u32 r = v.u + 0x7fffu + ((v.u >> 16) & 1u);
  return (ushort_t)(r >> 16);
}
__device__ __forceinline__ float bf2f(ushort_t h){
  union { u32 u; float f; } v; v.u = ((u32)h) << 16; return v.f;
}

// B=4096 T=32 C=180 H=6 HD=30 ; tokens = 131072
// ws layout (ushort elems): wqkv[6][3][32][192] | w1t[768][192] | w2t[192][768]
#define WQKV_ELEMS (576*192)
#define W1T_ELEMS  (768*192)
#define W2T_ELEMS  (192*768)

__global__ void prep_weights(const float* __restrict__ wq, const float* __restrict__ wk,
                             const float* __restrict__ wv, const float* __restrict__ w1,
                             const float* __restrict__ w2, ushort_t* __restrict__ ws){
  ushort_t* wqkv = ws;
  ushort_t* w1t = ws + WQKV_ELEMS;
  ushort_t* w2t = w1t + W1T_ELEMS;
  int tid = blockIdx.x * blockDim.x + threadIdx.x;
  int stride = gridDim.x * blockDim.x;
  for (int i = tid; i < WQKV_ELEMS; i += stride){
    int k = i % 192; int row = i / 192;
    int d = row & 31; int m = (row >> 5) % 3; int h = row / 96;
    float v = 0.f;
    if (d < 30 && k < 180){
      const float* W = (m == 0) ? wq : ((m == 1) ? wk : wv);
      v = W[(h*180 + k)*30 + d];
    }
    wqkv[i] = f2bf(v);
  }
  for (int i = tid; i < W1T_ELEMS; i += stride){
    int c = i % 192; int n = i / 192;
    float v = (n < 720 && c < 180) ? w1[c*720 + n] : 0.f;
    w1t[i] = f2bf(v);
  }
  for (int i = tid; i < W2T_ELEMS; i += stride){
    int c4 = i % 768; int n = i / 768;
    float v = (n < 180 && c4 < 720) ? w2[c4*180 + n] : 0.f;
    w2t[i] = f2bf(v);
  }
}

// ---------------- Kernel 1: LN1 + QKV + causal attention ; writes x2 = x+attn into d_out
__global__ __launch_bounds__(256, 2)
void attn_kernel(const float* __restrict__ x, const float* __restrict__ g1,
                 const float* __restrict__ be1, const ushort_t* __restrict__ wqkv,
                 float* __restrict__ xout){
  __shared__ ushort_t h_lds[64*200];     // LN1 out bf16, rows 64, stride 200 (cols>=180 zero)
  __shared__ ushort_t q_s[4][32*40];     // per-wave q rowmajor [t][d32], later P [t][s32]
  __shared__ ushort_t k_s[4][32*40];     // per-wave k rowmajor [s][d32]
  __shared__ ushort_t v_s[4][32*40];     // per-wave vT [d32][s]
  __shared__ float    l_s[4][32];        // per-wave softmax denom
  __shared__ ushort_t att[64*196];       // attn out bf16, [row][head*32+d]

  int tid = threadIdx.x;
  int wave = tid >> 6;
  int lane = tid & 63;
  int quad = lane >> 4;
  int c16 = lane & 15;
  long block0 = (long)blockIdx.x * 64;

  for (int i = tid; i < 64*200/2; i += 256) ((u32*)h_lds)[i] = 0u;
  __syncthreads();

  // LN1: 4 threads per row, 45 cols each
  int row = tid >> 2, sub = tid & 3;
  const float* xrow = x + (block0 + row) * 180;
  float s1 = 0.f, s2 = 0.f;
  #pragma unroll
  for (int i = 0; i < 45; i++){
    float v = xrow[sub*45 + i];
    s1 += v; s2 += v*v;
  }
  s1 += __shfl_xor(s1, 1); s1 += __shfl_xor(s1, 2);
  s2 += __shfl_xor(s2, 1); s2 += __shfl_xor(s2, 2);
  float mu = s1 * (1.f/180.f);
  float rstd = rsqrtf(s2 * (1.f/180.f) - mu*mu + 1e-5f);
  #pragma unroll
  for (int i = 0; i < 45; i++){
    int col = sub*45 + i;
    h_lds[row*200 + col] = f2bf((xrow[col] - mu) * rstd * g1[col] + be1[col]);
  }
  __syncthreads();

  int bb = wave & 1;    // batch within block
  int hg = wave >> 1;   // head group (3 heads each)
  ushort_t* qs = q_s[wave]; ushort_t* ks = k_s[wave]; ushort_t* vs = v_s[wave];
  float* ls = l_s[wave];

  for (int hh = 0; hh < 3; hh++){
    int head = hg*3 + hh;
    const ushort_t* wbase = wqkv + head*3*32*192;
    // ---- QKV: M=32 (this batch), N = [q0 q1 k0 k1 v0 v1] (6x16), K=192
    f32x4 acc[2][6];
    #pragma unroll
    for (int i=0;i<2;i++){
      #pragma unroll
      for (int j=0;j<6;j++) acc[i][j] = (f32x4)0.f;
    }
    #pragma unroll
    for (int kk = 0; kk < 6; kk++){
      int k0 = kk*32;
      short8 a[2];
      #pragma unroll
      for (int mt=0; mt<2; mt++)
        a[mt] = *(const short8*)(h_lds + (bb*32 + mt*16 + c16)*200 + k0 + quad*8);
      short8 b[6];
      #pragma unroll
      for (int nb=0; nb<6; nb++)
        b[nb] = *(const short8*)(wbase + ((nb>>1)*32 + (nb&1)*16 + c16)*192 + k0 + quad*8);
      #pragma unroll
      for (int mt=0; mt<2; mt++){
        #pragma unroll
        for (int nb=0; nb<6; nb++)
          acc[mt][nb] = MFMA16(a[mt], b[nb], acc[mt][nb]);
      }
    }
    // ---- store q,k rowmajor (scalar u16); v transposed (b64)
    #pragma unroll
    for (int mt=0; mt<2; mt++){
      #pragma unroll
      for (int nt=0; nt<2; nt++){
        #pragma unroll
        for (int r=0;r<4;r++){
          int t = mt*16 + quad*4 + r;
          int d = nt*16 + c16;
          qs[t*40 + d] = f2bf(acc[mt][nt][r]);
          ks[t*40 + d] = f2bf(acc[mt][2+nt][r]);
        }
        u32 p0 = (u32)f2bf(acc[mt][4+nt][0]) | ((u32)f2bf(acc[mt][4+nt][1]) << 16);
        u32 p1 = (u32)f2bf(acc[mt][4+nt][2]) | ((u32)f2bf(acc[mt][4+nt][3]) << 16);
        u64 pv = (u64)p0 | ((u64)p1 << 32);
        *(u64*)(vs + (nt*16 + c16)*40 + mt*16 + quad*4) = pv;   // vT[d][t0..t0+3]
      }
    }
    // ---- scores = q @ k^T (K=32, d30/31 are zero-padded)
    f32x4 sacc[2][2];
    #pragma unroll
    for (int i=0;i<2;i++){ sacc[i][0] = (f32x4)0.f; sacc[i][1] = (f32x4)0.f; }
    short8 aq[2], bk[2];
    #pragma unroll
    for (int mt=0;mt<2;mt++) aq[mt] = *(const short8*)(qs + (mt*16 + c16)*40 + quad*8);
    #pragma unroll
    for (int nt=0;nt<2;nt++) bk[nt] = *(const short8*)(ks + (nt*16 + c16)*40 + quad*8);
    #pragma unroll
    for (int mt=0;mt<2;mt++){
      #pragma unroll
      for (int nt=0;nt<2;nt++)
        sacc[mt][nt] = MFMA16(aq[mt], bk[nt], sacc[mt][nt]);
    }
    // ---- softmax (rows t in quads); unnormalized P overwrites qs; denom -> ls
    const float scl = 0.18257418583505537f;  // 30^-0.5
    #pragma unroll
    for (int mt=0;mt<2;mt++){
      #pragma unroll
      for (int r=0;r<4;r++){
        int t = mt*16 + quad*4 + r;
        float v0 = sacc[mt][0][r] * scl; if (c16 > t) v0 = -1e30f;
        float v1 = sacc[mt][1][r] * scl; if (16 + c16 > t) v1 = -1e30f;
        float m = fmaxf(v0, v1);
        m = fmaxf(m, __shfl_xor(m, 1));
        m = fmaxf(m, __shfl_xor(m, 2));
        m = fmaxf(m, __shfl_xor(m, 4));
        m = fmaxf(m, __shfl_xor(m, 8));
        float e0 = __expf(v0 - m), e1 = __expf(v1 - m);
        float sum = e0 + e1;
        sum += __shfl_xor(sum, 1); sum += __shfl_xor(sum, 2);
        sum += __shfl_xor(sum, 4); sum += __shfl_xor(sum, 8);
        qs[t*40 + c16] = f2bf(e0);
        qs[t*40 + 16 + c16] = f2bf(e1);
        if (c16 == 0) ls[t] = sum;
      }
    }
    // ---- outT[d][t] = vT @ P^T  (A=vT rowmajor, B=P rowmajor)
    f32x4 oacc[2][2];
    #pragma unroll
    for (int i=0;i<2;i++){ oacc[i][0] = (f32x4)0.f; oacc[i][1] = (f32x4)0.f; }
    short8 av[2], bp[2];
    #pragma unroll
    for (int dt=0;dt<2;dt++) av[dt] = *(const short8*)(vs + (dt*16 + c16)*40 + quad*8);
    #pragma unroll
    for (int tt=0;tt<2;tt++) bp[tt] = *(const short8*)(qs + (tt*16 + c16)*40 + quad*8);
    #pragma unroll
    for (int dt=0;dt<2;dt++){
      #pragma unroll
      for (int tt=0;tt<2;tt++)
        oacc[dt][tt] = MFMA16(av[dt], bp[tt], oacc[dt][tt]);
    }
    // ---- normalize by l and write att[row][head*32+d] (d=30,31 are zeros by construction)
    #pragma unroll
    for (int dt=0;dt<2;dt++){
      #pragma unroll
      for (int tt=0;tt<2;tt++){
        int t = tt*16 + c16;
        float linv = 1.f / ls[t];
        u32 p0 = (u32)f2bf(oacc[dt][tt][0]*linv) | ((u32)f2bf(oacc[dt][tt][1]*linv) << 16);
        u32 p1 = (u32)f2bf(oacc[dt][tt][2]*linv) | ((u32)f2bf(oacc[dt][tt][3]*linv) << 16);
        u64 pp = (u64)p0 | ((u64)p1 << 32);
        *(u64*)(att + (bb*32 + t)*196 + head*32 + dt*16 + quad*4) = pp;
      }
    }
  } // heads

  __syncthreads();
  // x2 = x + attn -> d_out
  #pragma unroll
  for (int i = 0; i < 45; i++){
    int col = sub*45 + i;
    int hd = col / 30;
    int d = col - hd*30;
    float a = bf2f(att[row*196 + hd*32 + d]);
    xout[(block0 + row)*180 + col] = xrow[col] + a;
  }
}

// ---------------- Kernel 2: LN2 + MLP ; in-place residual update of d_out
__global__ __launch_bounds__(256, 2)
void mlp_kernel(const float* __restrict__ g2, const float* __restrict__ be2,
                const float* __restrict__ b1, const float* __restrict__ b2,
                const ushort_t* __restrict__ w1t, const ushort_t* __restrict__ w2t,
                float* __restrict__ xio){
  __shared__ ushort_t h2[64*200];    // LN2 out bf16 (cols>=180 zero)
  __shared__ ushort_t act[64*200];   // relu(h2@w1+b1) chunk, rowmajor [token][192]
  int tid = threadIdx.x;
  int wave = tid >> 6, lane = tid & 63;
  int quad = lane >> 4, c16 = lane & 15;
  long row0 = (long)blockIdx.x * 64;

  for (int i = tid; i < 64*200/2; i += 256) ((u32*)h2)[i] = 0u;
  __syncthreads();

  int row = tid >> 2, sub = tid & 3;
  const float* xr = xio + (row0 + row)*180;
  float s1 = 0.f, s2 = 0.f;
  #pragma unroll
  for (int i = 0; i < 45; i++){
    float v = xr[sub*45 + i];
    s1 += v; s2 += v*v;
  }
  s1 += __shfl_xor(s1, 1); s1 += __shfl_xor(s1, 2);
  s2 += __shfl_xor(s2, 1); s2 += __shfl_xor(s2, 2);
  float mu = s1 * (1.f/180.f);
  float rstd = rsqrtf(s2 * (1.f/180.f) - mu*mu + 1e-5f);
  #pragma unroll
  for (int i = 0; i < 45; i++){
    int col = sub*45 + i;
    h2[row*200 + col] = f2bf((xr[col] - mu) * rstd * g2[col] + be2[col]);
  }
  __syncthreads();

  f32x4 outacc[4][3];
  #pragma unroll
  for (int i=0;i<4;i++){
    #pragma unroll
    for (int j=0;j<3;j++) outacc[i][j] = (f32x4)0.f;
  }

  for (int ch = 0; ch < 4; ch++){
    // ---- MLP1 transposed: actT[n4c][token] ; A = w1t (global), B = h2 (LDS)
    f32x4 aacc[3][4];
    #pragma unroll
    for (int i=0;i<3;i++){
      #pragma unroll
      for (int j=0;j<4;j++) aacc[i][j] = (f32x4)0.f;
    }
    #pragma unroll
    for (int kk=0; kk<6; kk++){
      int k0 = kk*32;
      short8 aw[3];
      #pragma unroll
      for (int mi=0; mi<3; mi++)
        aw[mi] = *(const short8*)(w1t + (size_t)(ch*192 + (wave*3+mi)*16 + c16)*192 + k0 + quad*8);
      short8 bh[4];
      #pragma unroll
      for (int tt=0; tt<4; tt++)
        bh[tt] = *(const short8*)(h2 + (tt*16 + c16)*200 + k0 + quad*8);
      #pragma unroll
      for (int mi=0; mi<3; mi++){
        #pragma unroll
        for (int tt=0; tt<4; tt++)
          aacc[mi][tt] = MFMA16(aw[mi], bh[tt], aacc[mi][tt]);
      }
    }
    __syncthreads();   // previous chunk's MLP2 reads of act done
    // bias + relu + pack to act rowmajor (b64 stores)
    #pragma unroll
    for (int mi=0; mi<3; mi++){
      int nb = ch*192 + (wave*3+mi)*16 + quad*4;
      f32x4 bias = (f32x4)0.f;
      if (nb < 720) bias = *(const f32x4*)(b1 + nb);
      #pragma unroll
      for (int tt=0; tt<4; tt++){
        int token = tt*16 + c16;
        float v0 = fmaxf(aacc[mi][tt][0] + bias[0], 0.f);
        float v1 = fmaxf(aacc[mi][tt][1] + bias[1], 0.f);
        float v2 = fmaxf(aacc[mi][tt][2] + bias[2], 0.f);
        float v3 = fmaxf(aacc[mi][tt][3] + bias[3], 0.f);
        u32 p0 = (u32)f2bf(v0) | ((u32)f2bf(v1) << 16);
        u32 p1 = (u32)f2bf(v2) | ((u32)f2bf(v3) << 16);
        u64 pp = (u64)p0 | ((u64)p1 << 32);
        *(u64*)(act + token*200 + (wave*3+mi)*16 + quad*4) = pp;
      }
    }
    __syncthreads();   // act ready
    // ---- MLP2: out += act @ w2chunk ; A = act (LDS), B = w2t (global)
    #pragma unroll
    for (int kk=0; kk<6; kk++){
      int k0 = kk*32;
      short8 aa[4];
      #pragma unroll
      for (int mt=0; mt<4; mt++)
        aa[mt] = *(const short8*)(act + (mt*16 + c16)*200 + k0 + quad*8);
      short8 bw[3];
      #pragma unroll
      for (int ntl=0; ntl<3; ntl++)
        bw[ntl] = *(const short8*)(w2t + (size_t)(wave*48 + ntl*16 + c16)*768 + ch*192 + k0 + quad*8);
      #pragma unroll
      for (int mt=0; mt<4; mt++){
        #pragma unroll
        for (int ntl=0; ntl<3; ntl++)
          outacc[mt][ntl] = MFMA16(aa[mt], bw[ntl], outacc[mt][ntl]);
      }
    }
  }
  // epilogue: out = x2 + mlp + b2 (in place)
  #pragma unroll
  for (int ntl=0; ntl<3; ntl++){
    int nout = wave*48 + ntl*16 + c16;
    if (nout < 180){
      float bias2 = b2[nout];
      #pragma unroll
      for (int mt=0; mt<4; mt++){
        #pragma unroll
        for (int r=0;r<4;r++){
          long token = row0 + mt*16 + quad*4 + r;
          long idx = token*180 + nout;
          xio[idx] = xio[idx] + outacc[mt][ntl][r] + bias2;
        }
      }
    }
  }
}

extern "C" void kernel_launch(void* const* d_in, const int* in_sizes, int n_in,
                              void* d_out, int out_size, void* d_ws, size_t ws_size,
                              hipStream_t stream) {
  const float* x   = (const float*)d_in[0];
  const float* wq  = (const float*)d_in[1];
  const float* wk  = (const float*)d_in[2];
  const float* wv  = (const float*)d_in[3];
  const float* g1  = (const float*)d_in[4];
  const float* be1 = (const float*)d_in[5];
  const float* g2  = (const float*)d_in[6];
  const float* be2 = (const float*)d_in[7];
  const float* w1  = (const float*)d_in[8];
  const float* b1  = (const float*)d_in[9];
  const float* w2  = (const float*)d_in[10];
  const float* b2  = (const float*)d_in[11];
  ushort_t* ws   = (ushort_t*)d_ws;
  ushort_t* wqkv = ws;
  ushort_t* w1t  = ws + WQKV_ELEMS;
  ushort_t* w2t  = w1t + W1T_ELEMS;
  float* out = (float*)d_out;

  prep_weights<<<256, 256, 0, stream>>>(wq, wk, wv, w1, w2, ws);
  attn_kernel<<<2048, 256, 0, stream>>>(x, g1, be1, wqkv, out);
  mlp_kernel<<<2048, 256, 0, stream>>>(g2, be2, b1, b2, w1t, w2t, out);
}